// Round 1
// baseline (313.920 us; speedup 1.0000x reference)
//
#include <hip/hip_runtime.h>
#include <stdint.h>

// ---- JAX PRNG scheme toggle -------------------------------------------------
// 1: threefry_partitionable=True (modern JAX default): bits[i] = x0^x1 of
//    threefry2x32(key, (hi32(i), lo32(i))), i = flat index (< 2^32 here).
// 0: legacy scheme: counts=iota(2^27), split in half -> pairs (i, i+2^26),
//    bits[i] = x0 for first half, x1 for second half.
#define JAX_PARTITIONABLE 1

namespace {

constexpr int G = 8;
constexpr int S = 4096;   // sequence length
constexpr int TT = 256;   // t-tile staged in LDS
constexpr int RPB = 16;   // rows per block
// SCALE * log2(e):  2^10.5 * 1.4426950408889634
constexpr float K2C = (float)(1448.15468787004945 * 1.44269504088896340736);

__device__ __forceinline__ uint32_t rotl32(uint32_t x, uint32_t n) {
  return (x << n) | (x >> (32u - n));
}

__device__ __forceinline__ void tfround(uint32_t& x0, uint32_t& x1, uint32_t r) {
  x0 += x1;
  x1 = rotl32(x1, r);
  x1 ^= x0;
}

// threefry2x32 with key (0, 42)  [jax.random.key(42) -> (hi,lo)=(0,42)]
__device__ __forceinline__ void threefry2x32(uint32_t c0, uint32_t c1,
                                             uint32_t& r0, uint32_t& r1) {
  const uint32_t ks0 = 0u;
  const uint32_t ks1 = 42u;
  const uint32_t ks2 = 0x1BD11BF0u;  // 0 ^ 42 ^ 0x1BD11BDA
  uint32_t x0 = c0 + ks0;
  uint32_t x1 = c1 + ks1;
  tfround(x0, x1, 13); tfround(x0, x1, 15); tfround(x0, x1, 26); tfround(x0, x1, 6);
  x0 += ks1; x1 += ks2 + 1u;
  tfround(x0, x1, 17); tfround(x0, x1, 29); tfround(x0, x1, 16); tfround(x0, x1, 24);
  x0 += ks2; x1 += ks0 + 2u;
  tfround(x0, x1, 13); tfround(x0, x1, 15); tfround(x0, x1, 26); tfround(x0, x1, 6);
  x0 += ks0; x1 += ks1 + 3u;
  tfround(x0, x1, 17); tfround(x0, x1, 29); tfround(x0, x1, 16); tfround(x0, x1, 24);
  x0 += ks1; x1 += ks2 + 4u;
  tfround(x0, x1, 13); tfround(x0, x1, 15); tfround(x0, x1, 26); tfround(x0, x1, 6);
  x0 += ks2; x1 += ks0 + 5u;
  r0 = x0; r1 = x1;
}

// keep element iff uniform(i) < 0.5  <=>  MSB(random word) == 0
__device__ __forceinline__ bool keep_mask(uint32_t i) {
#if JAX_PARTITIONABLE
  uint32_t a, b;
  threefry2x32(0u, i, a, b);   // hi32(index)=0 since total size = 2^27
  return (((a ^ b) >> 31) == 0u);
#else
  uint32_t a, b;
  if (i < 67108864u) {         // 2^26 = half of 2^27 counters
    threefry2x32(i, i + 67108864u, a, b);
    return ((a >> 31) == 0u);
  } else {
    threefry2x32(i - 67108864u, i, a, b);
    return ((b >> 31) == 0u);
  }
#endif
}

__global__ __launch_bounds__(256)
void fused_attn(const float* __restrict__ x1, const float* __restrict__ x2,
                const float* __restrict__ Wq, const float* __restrict__ bq,
                const float* __restrict__ Wk, const float* __restrict__ bk,
                const float* __restrict__ Wv, const float* __restrict__ bv,
                float* __restrict__ out) {
  // Transposed float2 layout: KT[d2][tt] holds (k[2*d2], k[2*d2+1]) of column tt.
  // b64 read bank = (2*tt) % 32 -> 16 stripe-lanes hit 16 distinct banks (free);
  // 4-lane same-address reads broadcast.
  __shared__ float2 KT[4][TT];
  __shared__ float2 VT[4][TT];

  const int g = blockIdx.x >> 8;        // 0..7
  const int stile = blockIdx.x & 255;   // 0..255
  const int tid = (int)threadIdx.x;
  const int r = tid >> 4;               // row within tile, 0..15
  const int j = tid & 15;               // t-stripe lane, 0..15
  const int srow = stile * RPB + r;

  // q for this row (weights via uniform scalar loads)
  float q[8];
  {
    const float* px = x1 + (size_t)(g * S + srow) * 3;
    const float a0 = px[0], a1 = px[1], a2 = px[2];
#pragma unroll
    for (int hh = 0; hh < 8; ++hh)
      q[hh] = bq[hh] + a0 * Wq[hh * 3 + 0] + a1 * Wq[hh * 3 + 1] + a2 * Wq[hh * 3 + 2];
  }

  float mrow = -3.0e38f;  // running max of log2-domain scores (avoid inf arith)
  float lrow = 0.0f;      // running sum of 2^(s2 - mrow) over ALL t (pre-dropout)
  float o[8];
#pragma unroll
  for (int d = 0; d < 8; ++d) o[d] = 0.0f;

  const uint32_t ibase = ((uint32_t)(g * S + srow)) << 12;  // *4096

  for (int tile = 0; tile < S / TT; ++tile) {
    const int t0 = tile * TT;
    __syncthreads();  // previous tile's LDS reads done before overwrite
    {
      // stage k,v for t = t0 + tid (recomputed from x: only 48 FMA)
      const int t = t0 + tid;
      const float* p2 = x2 + (size_t)(g * S + t) * 3;
      const float* p1 = x1 + (size_t)(g * S + t) * 3;
      const float b0 = p2[0], b1 = p2[1], b2 = p2[2];
      const float a0 = p1[0], a1 = p1[1], a2 = p1[2];
      float kk[8], vv[8];
#pragma unroll
      for (int hh = 0; hh < 8; ++hh) {
        kk[hh] = bk[hh] + b0 * Wk[hh * 3 + 0] + b1 * Wk[hh * 3 + 1] + b2 * Wk[hh * 3 + 2];
        vv[hh] = bv[hh] + a0 * Wv[hh * 3 + 0] + a1 * Wv[hh * 3 + 1] + a2 * Wv[hh * 3 + 2];
      }
#pragma unroll
      for (int d2 = 0; d2 < 4; ++d2) {
        KT[d2][tid] = make_float2(kk[2 * d2], kk[2 * d2 + 1]);
        VT[d2][tid] = make_float2(vv[2 * d2], vv[2 * d2 + 1]);
      }
    }
    __syncthreads();

    for (int mm = 0; mm < 16; ++mm) {
      const int tt = j + (mm << 4);
      const float2 k0 = KT[0][tt], k1 = KT[1][tt], k2 = KT[2][tt], k3 = KT[3][tt];
      float dot = (q[0] * k0.x + q[1] * k0.y) + (q[2] * k1.x + q[3] * k1.y)
                + (q[4] * k2.x + q[5] * k2.y) + (q[6] * k3.x + q[7] * k3.y);
      const float s2 = dot * K2C;  // log2-domain score
      if (s2 > mrow) {             // rare after warm-up (~ln(4096) times total)
        const float sc = exp2f(mrow - s2);
        lrow *= sc;
#pragma unroll
        for (int d = 0; d < 8; ++d) o[d] *= sc;
        mrow = s2;
      }
      const float p = exp2f(s2 - mrow);
      lrow += p;  // denominator counts ALL t (dropout applied after softmax)
      if (p > 0.0f) {
        // mask only matters when p contributes; skips the 72-inst threefry
        // for the vast majority of (ultra-peaked-softmax) zero lanes
        if (keep_mask(ibase + (uint32_t)(t0 + tt))) {
          const float2 v0 = VT[0][tt], v1 = VT[1][tt], v2 = VT[2][tt], v3 = VT[3][tt];
          o[0] += p * v0.x; o[1] += p * v0.y;
          o[2] += p * v1.x; o[3] += p * v1.y;
          o[4] += p * v2.x; o[5] += p * v2.y;
          o[6] += p * v3.x; o[7] += p * v3.y;
        }
      }
    }
  }

  // merge (m, l, o[8]) across the 16 stripe-lanes of each row (in-wave xor shuffles)
#pragma unroll
  for (int msk = 1; msk < 16; msk <<= 1) {
    const float m2 = __shfl_xor(mrow, msk, 64);
    const float l2 = __shfl_xor(lrow, msk, 64);
    const float mn = fmaxf(mrow, m2);
    const float sa = exp2f(mrow - mn);
    const float sb = exp2f(m2 - mn);
    lrow = lrow * sa + l2 * sb;
#pragma unroll
    for (int d = 0; d < 8; ++d) {
      const float o2 = __shfl_xor(o[d], msk, 64);
      o[d] = o[d] * sa + o2 * sb;
    }
    mrow = mn;
  }

  if (j == 0) {
    const float inv = 2.0f / lrow;  // includes 1/(1-p_drop) = 2
    float4* po = (float4*)(out + (size_t)(g * S + srow) * 8);
    po[0] = make_float4(o[0] * inv, o[1] * inv, o[2] * inv, o[3] * inv);
    po[1] = make_float4(o[4] * inv, o[5] * inv, o[6] * inv, o[7] * inv);
  }
}

}  // namespace

extern "C" void kernel_launch(void* const* d_in, const int* in_sizes, int n_in,
                              void* d_out, int out_size, void* d_ws, size_t ws_size,
                              hipStream_t stream) {
  (void)in_sizes; (void)n_in; (void)d_ws; (void)ws_size; (void)out_size;
  const float* x1 = (const float*)d_in[0];
  const float* x2 = (const float*)d_in[1];
  const float* Wq = (const float*)d_in[2];
  const float* bq = (const float*)d_in[3];
  const float* Wk = (const float*)d_in[4];
  const float* bk = (const float*)d_in[5];
  const float* Wv = (const float*)d_in[6];
  const float* bv = (const float*)d_in[7];
  float* out = (float*)d_out;

  // 8 groups x (4096/16) row tiles
  fused_attn<<<dim3(G * (S / RPB)), dim3(256), 0, stream>>>(
      x1, x2, Wq, bq, Wk, bk, Wv, bv, out);
}

// Round 2
// 160.178 us; speedup vs baseline: 1.9598x; 1.9598x over previous
//
#include <hip/hip_runtime.h>
#include <stdint.h>

namespace {

constexpr int G = 8;
constexpr int S = 4096;   // sequence length
constexpr int TT = 256;   // t-tile staged in LDS
constexpr int RPB = 16;   // rows per block
// SCALE * log2(e):  2^10.5 * 1.4426950408889634
constexpr float K2C = (float)(1448.15468787004945 * 1.44269504088896340736);
// terms with s2 < rowmax - CUT contribute < 2^-32 to l (l >= 1) and to the
// kept sums -> invisible in fp32. Keeps the slow path ultra-rare.
constexpr float CUT = 32.0f;

__device__ __forceinline__ uint32_t rotl32(uint32_t x, uint32_t n) {
  return (x << n) | (x >> (32u - n));
}

__device__ __forceinline__ void tfround(uint32_t& x0, uint32_t& x1, uint32_t r) {
  x0 += x1;
  x1 = rotl32(x1, r);
  x1 ^= x0;
}

// threefry2x32 with key (0, 42)  [jax.random.key(42) -> (hi,lo)=(0,42)]
__device__ __forceinline__ void threefry2x32(uint32_t c0, uint32_t c1,
                                             uint32_t& r0, uint32_t& r1) {
  const uint32_t ks0 = 0u;
  const uint32_t ks1 = 42u;
  const uint32_t ks2 = 0x1BD11BF0u;  // 0 ^ 42 ^ 0x1BD11BDA
  uint32_t x0 = c0 + ks0;
  uint32_t x1 = c1 + ks1;
  tfround(x0, x1, 13); tfround(x0, x1, 15); tfround(x0, x1, 26); tfround(x0, x1, 6);
  x0 += ks1; x1 += ks2 + 1u;
  tfround(x0, x1, 17); tfround(x0, x1, 29); tfround(x0, x1, 16); tfround(x0, x1, 24);
  x0 += ks2; x1 += ks0 + 2u;
  tfround(x0, x1, 13); tfround(x0, x1, 15); tfround(x0, x1, 26); tfround(x0, x1, 6);
  x0 += ks0; x1 += ks1 + 3u;
  tfround(x0, x1, 17); tfround(x0, x1, 29); tfround(x0, x1, 16); tfround(x0, x1, 24);
  x0 += ks1; x1 += ks2 + 4u;
  tfround(x0, x1, 13); tfround(x0, x1, 15); tfround(x0, x1, 26); tfround(x0, x1, 6);
  x0 += ks2; x1 += ks0 + 5u;
  r0 = x0; r1 = x1;
}

// keep element iff uniform(i) < 0.5  <=>  MSB(x0^x1) == 0  (partitionable PRNG)
__device__ __forceinline__ bool keep_mask(uint32_t i) {
  uint32_t a, b;
  threefry2x32(0u, i, a, b);   // hi32(index)=0 since total size = 2^27
  return (((a ^ b) >> 31) == 0u);
}

__global__ __launch_bounds__(256)
void fused_attn(const float* __restrict__ x1, const float* __restrict__ x2,
                const float* __restrict__ Wq, const float* __restrict__ bq,
                const float* __restrict__ Wk, const float* __restrict__ bk,
                const float* __restrict__ Wv, const float* __restrict__ bv,
                float* __restrict__ out) {
  __shared__ float4 X2[TT];  // x2[t] staged (w-component unused)
  __shared__ float4 X1[TT];  // x1[t] staged (pass B only, read in rare path)

  const int g = blockIdx.x >> 8;        // 0..7
  const int stile = blockIdx.x & 255;   // 0..255
  const int tid = (int)threadIdx.x;
  const int r = tid >> 4;               // row within tile, 0..15
  const int j = tid & 15;               // t-stripe lane, 0..15
  const int srow = stile * RPB + r;

  // q for this row, then low-rank fold: s2(t) = cK . x2[t] + c3  (log2 domain,
  // SCALE*log2e already folded in).
  float cK0, cK1, cK2, c3;
  float q[8];
  {
    const float* px = x1 + (size_t)(g * S + srow) * 3;
    const float a0 = px[0], a1 = px[1], a2 = px[2];
#pragma unroll
    for (int hh = 0; hh < 8; ++hh)
      q[hh] = bq[hh] + a0 * Wq[hh * 3 + 0] + a1 * Wq[hh * 3 + 1] + a2 * Wq[hh * 3 + 2];
    float t0 = 0.f, t1 = 0.f, t2 = 0.f, t3 = 0.f;
#pragma unroll
    for (int hh = 0; hh < 8; ++hh) {
      t0 += q[hh] * Wk[hh * 3 + 0];
      t1 += q[hh] * Wk[hh * 3 + 1];
      t2 += q[hh] * Wk[hh * 3 + 2];
      t3 += q[hh] * bk[hh];
    }
    cK0 = t0 * K2C; cK1 = t1 * K2C; cK2 = t2 * K2C; c3 = t3 * K2C;
  }

  // ---------------- pass A: exact row max of s2 ----------------
  float mrow = -3.0e38f;
  for (int tile = 0; tile < S / TT; ++tile) {
    __syncthreads();
    {
      const float* p2 = x2 + (size_t)(g * S + tile * TT + tid) * 3;
      X2[tid] = make_float4(p2[0], p2[1], p2[2], 0.0f);
    }
    __syncthreads();
#pragma unroll
    for (int mm = 0; mm < 16; ++mm) {
      const float4 b = X2[j + (mm << 4)];
      const float s2 = fmaf(cK0, b.x, fmaf(cK1, b.y, fmaf(cK2, b.z, c3)));
      mrow = fmaxf(mrow, s2);
    }
  }
  // merge max across the 16 stripe-lanes of each row (butterfly -> all lanes)
#pragma unroll
  for (int msk = 1; msk < 16; msk <<= 1)
    mrow = fmaxf(mrow, __shfl_xor(mrow, msk, 64));

  // ---------------- pass B: denominator + kept-weighted x1 sums ----------------
  float lrow = 0.0f;      // sum of 2^(s2-mrow) over all t (pre-dropout)
  float lkeep = 0.0f;     // sum of kept p
  float oa0 = 0.0f, oa1 = 0.0f, oa2 = 0.0f;  // sum of kept p * x1[t]
  const float cut = mrow - CUT;
  const uint32_t ibase = ((uint32_t)(g * S + srow)) << 12;  // *4096

  for (int tile = 0; tile < S / TT; ++tile) {
    const int t0 = tile * TT;
    __syncthreads();
    {
      const int t = t0 + tid;
      const float* p2 = x2 + (size_t)(g * S + t) * 3;
      const float* p1 = x1 + (size_t)(g * S + t) * 3;
      X2[tid] = make_float4(p2[0], p2[1], p2[2], 0.0f);
      X1[tid] = make_float4(p1[0], p1[1], p1[2], 0.0f);
    }
    __syncthreads();
#pragma unroll
    for (int mm = 0; mm < 16; ++mm) {
      const int tt = j + (mm << 4);
      const float4 b = X2[tt];
      const float s2 = fmaf(cK0, b.x, fmaf(cK1, b.y, fmaf(cK2, b.z, c3)));
      const bool act = (s2 > cut);
      if (__any(act)) {        // wave-uniform branch: taken ~2% of iterations
        if (act) {
          const float p = exp2f(s2 - mrow);
          lrow += p;
          if (keep_mask(ibase + (uint32_t)(t0 + tt))) {
            const float4 a = X1[tt];
            lkeep += p;
            oa0 += p * a.x; oa1 += p * a.y; oa2 += p * a.z;
          }
        }
      }
    }
  }

  // merge (l, lkeep, oa0..2) across the 16 stripe-lanes of each row
#pragma unroll
  for (int msk = 1; msk < 16; msk <<= 1) {
    lrow  += __shfl_xor(lrow,  msk, 64);
    lkeep += __shfl_xor(lkeep, msk, 64);
    oa0   += __shfl_xor(oa0,   msk, 64);
    oa1   += __shfl_xor(oa1,   msk, 64);
    oa2   += __shfl_xor(oa2,   msk, 64);
  }

  if (j == 0) {
    const float sc = 2.0f / lrow;  // includes 1/(1-p_drop) = 2
    float o[8];
#pragma unroll
    for (int hh = 0; hh < 8; ++hh) {
      o[hh] = (bv[hh] * lkeep + Wv[hh * 3 + 0] * oa0 + Wv[hh * 3 + 1] * oa1 +
               Wv[hh * 3 + 2] * oa2) * sc;
    }
    float4* po = (float4*)(out + (size_t)(g * S + srow) * 8);
    po[0] = make_float4(o[0], o[1], o[2], o[3]);
    po[1] = make_float4(o[4], o[5], o[6], o[7]);
  }
}

}  // namespace

extern "C" void kernel_launch(void* const* d_in, const int* in_sizes, int n_in,
                              void* d_out, int out_size, void* d_ws, size_t ws_size,
                              hipStream_t stream) {
  (void)in_sizes; (void)n_in; (void)d_ws; (void)ws_size; (void)out_size;
  const float* x1 = (const float*)d_in[0];
  const float* x2 = (const float*)d_in[1];
  const float* Wq = (const float*)d_in[2];
  const float* bq = (const float*)d_in[3];
  const float* Wk = (const float*)d_in[4];
  const float* bk = (const float*)d_in[5];
  const float* Wv = (const float*)d_in[6];
  const float* bv = (const float*)d_in[7];
  float* out = (float*)d_out;

  fused_attn<<<dim3(G * (S / RPB)), dim3(256), 0, stream>>>(
      x1, x2, Wq, bq, Wk, bk, Wv, bv, out);
}

// Round 4
// 115.829 us; speedup vs baseline: 2.7102x; 1.3829x over previous
//
#include <hip/hip_runtime.h>
#include <stdint.h>

namespace {

constexpr int G = 8;
constexpr int S = 4096;   // sequence length
constexpr int RPB = 16;   // rows per block
// SCALE * log2(e):  2^10.5 * 1.4426950408889634
constexpr float K2C = (float)(1448.15468787004945 * 1.44269504088896340736);
// terms with d < -CUT contribute < 2^-32 to l (l >= 1) -> invisible in fp32
constexpr float CUT = 32.0f;

__device__ __forceinline__ uint32_t rotl32(uint32_t x, uint32_t n) {
  return (x << n) | (x >> (32u - n));
}

__device__ __forceinline__ void tfround(uint32_t& x0, uint32_t& x1, uint32_t r) {
  x0 += x1;
  x1 = rotl32(x1, r);
  x1 ^= x0;
}

// threefry2x32 with key (0, 42)  [jax.random.key(42) -> (hi,lo)=(0,42)]
__device__ __forceinline__ void threefry2x32(uint32_t c0, uint32_t c1,
                                             uint32_t& r0, uint32_t& r1) {
  const uint32_t ks0 = 0u;
  const uint32_t ks1 = 42u;
  const uint32_t ks2 = 0x1BD11BF0u;  // 0 ^ 42 ^ 0x1BD11BDA
  uint32_t x0 = c0 + ks0;
  uint32_t x1 = c1 + ks1;
  tfround(x0, x1, 13); tfround(x0, x1, 15); tfround(x0, x1, 26); tfround(x0, x1, 6);
  x0 += ks1; x1 += ks2 + 1u;
  tfround(x0, x1, 17); tfround(x0, x1, 29); tfround(x0, x1, 16); tfround(x0, x1, 24);
  x0 += ks2; x1 += ks0 + 2u;
  tfround(x0, x1, 13); tfround(x0, x1, 15); tfround(x0, x1, 26); tfround(x0, x1, 6);
  x0 += ks0; x1 += ks1 + 3u;
  tfround(x0, x1, 17); tfround(x0, x1, 29); tfround(x0, x1, 16); tfround(x0, x1, 24);
  x0 += ks1; x1 += ks2 + 4u;
  tfround(x0, x1, 13); tfround(x0, x1, 15); tfround(x0, x1, 26); tfround(x0, x1, 6);
  x0 += ks2; x1 += ks0 + 5u;
  r0 = x0; r1 = x1;
}

// keep element iff uniform(i) < 0.5  <=>  MSB(x0^x1) == 0  (partitionable PRNG)
__device__ __forceinline__ bool keep_mask(uint32_t i) {
  uint32_t a, b;
  threefry2x32(0u, i, a, b);   // hi32(index)=0 since total size = 2^27
  return (((a ^ b) >> 31) == 0u);
}

__global__ __launch_bounds__(256)
void fused_attn(const float* __restrict__ x1, const float* __restrict__ x2,
                const float* __restrict__ Wq, const float* __restrict__ bq,
                const float* __restrict__ Wk, const float* __restrict__ bk,
                const float* __restrict__ Wv, const float* __restrict__ bv,
                float* __restrict__ out) {
  __shared__ __align__(16) float X2S[S * 3];  // whole x2(g), 48 KB
  __shared__ float4 CKs[RPB];                  // per-row folded K coeffs
  __shared__ float  MW[4][8];                  // per-wave row maxima
  __shared__ float  WACC[4][8][5];             // per-WAVE accumulators (no atomics)

  const int g = blockIdx.x >> 8;        // 0..7
  const int stile = blockIdx.x & 255;   // 0..255
  const int row0 = stile * RPB;
  const int tid = (int)threadIdx.x;
  const int wave = tid >> 6;
  const int lane = tid & 63;
  const int rowbase = (wave >> 1) << 3;  // waves 0,1 -> rows 0-7; waves 2,3 -> 8-15
  const int qtr = wave & 1;              // which half of S this wave scans

  if (tid < 4 * 8 * 5) ((float*)WACC)[tid] = 0.0f;

  // threads 0..15: build per-row low-rank coeffs  s2(t) = cK . x2[t] + c3
  if (tid < RPB) {
    const float* px = x1 + (size_t)(g * S + row0 + tid) * 3;
    const float a0 = px[0], a1 = px[1], a2 = px[2];
    float q[8];
#pragma unroll
    for (int h = 0; h < 8; ++h)
      q[h] = bq[h] + a0 * Wq[h * 3 + 0] + a1 * Wq[h * 3 + 1] + a2 * Wq[h * 3 + 2];
    float t0 = 0.f, t1 = 0.f, t2 = 0.f, t3 = 0.f;
#pragma unroll
    for (int h = 0; h < 8; ++h) {
      t0 += q[h] * Wk[h * 3 + 0];
      t1 += q[h] * Wk[h * 3 + 1];
      t2 += q[h] * Wk[h * 3 + 2];
      t3 += q[h] * bk[h];
    }
    CKs[tid] = make_float4(t0 * K2C, t1 * K2C, t2 * K2C, t3 * K2C);
  }

  // stage x2(g) into LDS: 12 independent float4 loads per thread (MLP=12)
  {
    const float4* src = (const float4*)(x2 + (size_t)g * S * 3);
    float4* dst = (float4*)X2S;
    float4 tmp[12];
#pragma unroll
    for (int i = 0; i < 12; ++i) tmp[i] = src[tid + (i << 8)];
#pragma unroll
    for (int i = 0; i < 12; ++i) dst[tid + (i << 8)] = tmp[i];
  }
  __syncthreads();

  float4 CK[8];
#pragma unroll
  for (int h = 0; h < 8; ++h) CK[h] = CKs[rowbase + h];

  const int xbase = qtr * (S / 2) * 3 + lane * 3;

  // ---------------- pass A: exact row max (x2 from LDS) ----------------
  float m[8];
#pragma unroll
  for (int h = 0; h < 8; ++h) m[h] = -3.0e38f;
#pragma unroll 4
  for (int c = 0; c < S / 2 / 64; ++c) {   // 32 chunks of 64 t
    const int idx = xbase + c * 192;
    const float bx = X2S[idx], by = X2S[idx + 1], bz = X2S[idx + 2];
#pragma unroll
    for (int h = 0; h < 8; ++h)
      m[h] = fmaxf(m[h], fmaf(CK[h].x, bx, fmaf(CK[h].y, by, fmaf(CK[h].z, bz, CK[h].w))));
  }
#pragma unroll
  for (int msk = 1; msk < 64; msk <<= 1) {
#pragma unroll
    for (int h = 0; h < 8; ++h) m[h] = fmaxf(m[h], __shfl_xor(m[h], msk, 64));
  }
  if (lane == 0) {
#pragma unroll
    for (int h = 0; h < 8; ++h) MW[wave][h] = m[h];
  }
  __syncthreads();
  {
    const int pb = (wave >> 1) << 1;  // wave pair sharing my rows
#pragma unroll
    for (int h = 0; h < 8; ++h) {
      const float rm = fmaxf(MW[pb][h], MW[pb + 1][h]);
      CK[h].w -= rm;  // fold rowmax into c3 -> inner loop yields d = s2 - rowmax
    }
  }

  // ---------------- pass B: denominator + kept-weighted x1 sums ----------------
  // Per-wave REGISTER accumulators; single fixed-order butterfly at the end.
  float lr[8], lk[8], o0[8], o1[8], o2[8];
#pragma unroll
  for (int h = 0; h < 8; ++h) { lr[h] = 0.f; lk[h] = 0.f; o0[h] = 0.f; o1[h] = 0.f; o2[h] = 0.f; }
  const uint32_t rb0 = (uint32_t)(g * S + row0 + rowbase);

#pragma unroll 2
  for (int c = 0; c < S / 2 / 64; ++c) {
    const int idx = xbase + c * 192;
    const float bx = X2S[idx], by = X2S[idx + 1], bz = X2S[idx + 2];
    float d[8];
#pragma unroll
    for (int h = 0; h < 8; ++h)
      d[h] = fmaf(CK[h].x, bx, fmaf(CK[h].y, by, fmaf(CK[h].z, bz, CK[h].w)));
    float mx = d[0];
#pragma unroll
    for (int h = 1; h < 8; ++h) mx = fmaxf(mx, d[h]);
    if (__any(mx > -CUT)) {           // rare: survivors ~1-3 per row total
      const int t = qtr * (S / 2) + (c << 6) + lane;
#pragma unroll
      for (int h = 0; h < 8; ++h) {
        if (__any(d[h] > -CUT)) {
          if (d[h] > -CUT) {
            const float pr = exp2f(d[h]);
            lr[h] += pr;
            if (keep_mask(((rb0 + (uint32_t)h) << 12) + (uint32_t)t)) {
              const float* pa = x1 + (size_t)(g * S + t) * 3;
              lk[h] += pr;
              o0[h] += pr * pa[0]; o1[h] += pr * pa[1]; o2[h] += pr * pa[2];
            }
          }
        }
      }
    }
  }

  // fixed-order 64-lane butterfly (deterministic), then lane 0 -> per-wave slot
#pragma unroll
  for (int msk = 1; msk < 64; msk <<= 1) {
#pragma unroll
    for (int h = 0; h < 8; ++h) {
      lr[h] += __shfl_xor(lr[h], msk, 64);
      lk[h] += __shfl_xor(lk[h], msk, 64);
      o0[h] += __shfl_xor(o0[h], msk, 64);
      o1[h] += __shfl_xor(o1[h], msk, 64);
      o2[h] += __shfl_xor(o2[h], msk, 64);
    }
  }
  if (lane == 0) {
#pragma unroll
    for (int h = 0; h < 8; ++h) {
      WACC[wave][h][0] = lr[h];
      WACC[wave][h][1] = lk[h];
      WACC[wave][h][2] = o0[h];
      WACC[wave][h][3] = o1[h];
      WACC[wave][h][4] = o2[h];
    }
  }
  __syncthreads();

  // epilogue: combine the two wave slots per row in FIXED order, project via Wv
  if (tid < RPB) {
    const int pw = (tid >> 3) << 1;   // rows 0-7 -> waves 0,1; rows 8-15 -> 2,3
    const int hr = tid & 7;
    const float l  = WACC[pw][hr][0] + WACC[pw + 1][hr][0];
    const float lkp = WACC[pw][hr][1] + WACC[pw + 1][hr][1];
    const float a0 = WACC[pw][hr][2] + WACC[pw + 1][hr][2];
    const float a1 = WACC[pw][hr][3] + WACC[pw + 1][hr][3];
    const float a2 = WACC[pw][hr][4] + WACC[pw + 1][hr][4];
    const float sc = 2.0f / l;  // includes 1/(1-p_drop) = 2
    float o[8];
#pragma unroll
    for (int h = 0; h < 8; ++h)
      o[h] = (bv[h] * lkp + Wv[h * 3 + 0] * a0 + Wv[h * 3 + 1] * a1 +
              Wv[h * 3 + 2] * a2) * sc;
    float4* po = (float4*)(out + (size_t)(g * S + row0 + tid) * 8);
    po[0] = make_float4(o[0], o[1], o[2], o[3]);
    po[1] = make_float4(o[4], o[5], o[6], o[7]);
  }
}

}  // namespace

extern "C" void kernel_launch(void* const* d_in, const int* in_sizes, int n_in,
                              void* d_out, int out_size, void* d_ws, size_t ws_size,
                              hipStream_t stream) {
  (void)in_sizes; (void)n_in; (void)d_ws; (void)ws_size; (void)out_size;
  const float* x1 = (const float*)d_in[0];
  const float* x2 = (const float*)d_in[1];
  const float* Wq = (const float*)d_in[2];
  const float* bq = (const float*)d_in[3];
  const float* Wk = (const float*)d_in[4];
  const float* bk = (const float*)d_in[5];
  const float* Wv = (const float*)d_in[6];
  const float* bv = (const float*)d_in[7];
  float* out = (float*)d_out;

  fused_attn<<<dim3(G * (S / RPB)), dim3(256), 0, stream>>>(
      x1, x2, Wq, bq, Wk, bk, Wv, bv, out);
}

// Round 5
// 102.766 us; speedup vs baseline: 3.0547x; 1.1271x over previous
//
#include <hip/hip_runtime.h>
#include <stdint.h>

namespace {

constexpr int G = 8;
constexpr int S = 4096;   // sequence length
constexpr int RPB = 16;   // rows per block
constexpr int QT = 1024;  // t per staged quarter (12 KB SoA)
// SCALE * log2(e):  2^10.5 * 1.4426950408889634
constexpr float K2C = (float)(1448.15468787004945 * 1.44269504088896340736);
// terms with d < -CUT contribute < 2^-32 each to l (l >= 1) -> invisible in fp32
constexpr float CUT = 32.0f;

__device__ __forceinline__ uint32_t rotl32(uint32_t x, uint32_t n) {
  return (x << n) | (x >> (32u - n));
}

__device__ __forceinline__ void tfround(uint32_t& x0, uint32_t& x1, uint32_t r) {
  x0 += x1;
  x1 = rotl32(x1, r);
  x1 ^= x0;
}

// threefry2x32 with key (0, 42). Called only on wave-uniform inputs ->
// compiler scalarizes to SALU (runs parallel to VALU).
__device__ __forceinline__ void threefry2x32(uint32_t c0, uint32_t c1,
                                             uint32_t& r0, uint32_t& r1) {
  const uint32_t ks0 = 0u;
  const uint32_t ks1 = 42u;
  const uint32_t ks2 = 0x1BD11BF0u;  // 0 ^ 42 ^ 0x1BD11BDA
  uint32_t x0 = c0 + ks0;
  uint32_t x1 = c1 + ks1;
  tfround(x0, x1, 13); tfround(x0, x1, 15); tfround(x0, x1, 26); tfround(x0, x1, 6);
  x0 += ks1; x1 += ks2 + 1u;
  tfround(x0, x1, 17); tfround(x0, x1, 29); tfround(x0, x1, 16); tfround(x0, x1, 24);
  x0 += ks2; x1 += ks0 + 2u;
  tfround(x0, x1, 13); tfround(x0, x1, 15); tfround(x0, x1, 26); tfround(x0, x1, 6);
  x0 += ks0; x1 += ks1 + 3u;
  tfround(x0, x1, 17); tfround(x0, x1, 29); tfround(x0, x1, 16); tfround(x0, x1, 24);
  x0 += ks1; x1 += ks2 + 4u;
  tfround(x0, x1, 13); tfround(x0, x1, 15); tfround(x0, x1, 26); tfround(x0, x1, 6);
  x0 += ks2; x1 += ks0 + 5u;
  r0 = x0; r1 = x1;
}

// keep element iff uniform(i) < 0.5  <=>  MSB(x0^x1) == 0  (partitionable PRNG)
__device__ __forceinline__ bool keep_mask(uint32_t i) {
  uint32_t a, b;
  threefry2x32(0u, i, a, b);   // hi32(index)=0 since total size = 2^27
  return (((a ^ b) >> 31) == 0u);
}

__global__ __launch_bounds__(256, 4)
void fused_attn(const float* __restrict__ x1, const float* __restrict__ x2,
                const float* __restrict__ Wq, const float* __restrict__ bq,
                const float* __restrict__ Wk, const float* __restrict__ bk,
                const float* __restrict__ Wv, const float* __restrict__ bv,
                float* __restrict__ out) {
  __shared__ __align__(16) float XS[QT];   // SoA quarter stage: x comp
  __shared__ __align__(16) float YS[QT];
  __shared__ __align__(16) float ZS[QT];
  __shared__ float4 CKs[RPB];              // per-row folded K coeffs
  __shared__ float  MW[4][8];              // per-wave row maxima
  __shared__ float  WACC[4][8][5];         // per-wave accumulators

  const int g = blockIdx.x >> 8;        // 0..7
  const int stile = blockIdx.x & 255;   // 0..255
  const int row0 = stile * RPB;
  const int tid = (int)threadIdx.x;
  const int wave = tid >> 6;
  const int lane = tid & 63;
  const int rowbase = (wave >> 1) << 3;  // waves 0,1 -> rows 0-7; 2,3 -> 8-15
  const int half = wave & 1;             // 512-t slice within each quarter

  const float* x2g = x2 + (size_t)g * S * 3;
  const float* x1g = x1 + (size_t)g * S * 3;

  // threads 0..15: per-row low-rank coeffs  s2(t) = cK . x2[t] + c3
  if (tid < RPB) {
    const float* px = x1g + (size_t)(row0 + tid) * 3;
    const float a0 = px[0], a1 = px[1], a2 = px[2];
    float q[8];
#pragma unroll
    for (int h = 0; h < 8; ++h)
      q[h] = bq[h] + a0 * Wq[h * 3 + 0] + a1 * Wq[h * 3 + 1] + a2 * Wq[h * 3 + 2];
    float t0 = 0.f, t1 = 0.f, t2 = 0.f, t3 = 0.f;
#pragma unroll
    for (int h = 0; h < 8; ++h) {
      t0 += q[h] * Wk[h * 3 + 0];
      t1 += q[h] * Wk[h * 3 + 1];
      t2 += q[h] * Wk[h * 3 + 2];
      t3 += q[h] * bk[h];
    }
    CKs[tid] = make_float4(t0 * K2C, t1 * K2C, t2 * K2C, t3 * K2C);
  }
  __syncthreads();

  float4 CK[8];
#pragma unroll
  for (int h = 0; h < 8; ++h) CK[h] = CKs[rowbase + h];

  float4* X4 = (float4*)XS;
  float4* Y4 = (float4*)YS;
  float4* Z4 = (float4*)ZS;

  // stage quarter q into SoA LDS: thread owns t-group [4*tid, 4*tid+4)
  auto stage = [&](int q) {
    const float4* src = (const float4*)(x2g + (size_t)q * QT * 3);
    const float4 f0 = src[tid * 3 + 0];
    const float4 f1 = src[tid * 3 + 1];
    const float4 f2 = src[tid * 3 + 2];
    X4[tid] = make_float4(f0.x, f0.w, f1.z, f2.y);
    Y4[tid] = make_float4(f0.y, f1.x, f1.w, f2.z);
    Z4[tid] = make_float4(f0.z, f1.y, f2.x, f2.w);
  };

  // ---------------- phase 1: exact row max over full S ----------------
  float m[8];
#pragma unroll
  for (int h = 0; h < 8; ++h) m[h] = -3.0e38f;

  for (int q = 0; q < 4; ++q) {
    __syncthreads();   // prior quarter's reads done before overwrite
    stage(q);
    __syncthreads();
#pragma unroll
    for (int grp = 0; grp < 2; ++grp) {
      const int i4 = half * 128 + (grp << 6) + lane;  // conflict-free b128
      const float4 fx = X4[i4], fy = Y4[i4], fz = Z4[i4];
      const float bxa[4] = {fx.x, fx.y, fx.z, fx.w};
      const float bya[4] = {fy.x, fy.y, fy.z, fy.w};
      const float bza[4] = {fz.x, fz.y, fz.z, fz.w};
#pragma unroll
      for (int e = 0; e < 4; ++e) {
        const float bx = bxa[e], by = bya[e], bz = bza[e];
#pragma unroll
        for (int h = 0; h < 8; ++h)
          m[h] = fmaxf(m[h], fmaf(CK[h].x, bx,
                       fmaf(CK[h].y, by, fmaf(CK[h].z, bz, CK[h].w))));
      }
    }
  }
  // single cross-lane butterfly (48 swizzles total)
#pragma unroll
  for (int msk = 1; msk < 64; msk <<= 1) {
#pragma unroll
    for (int h = 0; h < 8; ++h) m[h] = fmaxf(m[h], __shfl_xor(m[h], msk, 64));
  }
  if (lane == 0) {
#pragma unroll
    for (int h = 0; h < 8; ++h) MW[wave][h] = m[h];
  }
  __syncthreads();
  // combine with partner wave (same rows, other column half); fold into CK.w
#pragma unroll
  for (int h = 0; h < 8; ++h) {
    const float rm = fmaxf(m[h], MW[wave ^ 1][h]);
    CK[h].w -= rm;   // inner loop now yields d = s2 - rowmax (exact, global)
  }

  // ---------------- phase 2: accumulate (sparse, wave-uniform events) --------
  float lr[8], lk[8], o0[8], o1[8], o2[8];
#pragma unroll
  for (int h = 0; h < 8; ++h) { lr[h] = 0.f; lk[h] = 0.f; o0[h] = 0.f; o1[h] = 0.f; o2[h] = 0.f; }
  const uint32_t rg0 = (uint32_t)(g * S + row0 + rowbase);  // global row base

  for (int q = 0; q < 4; ++q) {
    __syncthreads();
    stage(q);
    __syncthreads();
#pragma unroll
    for (int grp = 0; grp < 2; ++grp) {
      const int i4 = half * 128 + (grp << 6) + lane;
      const float4 fx = X4[i4], fy = Y4[i4], fz = Z4[i4];
      const float bxa[4] = {fx.x, fx.y, fx.z, fx.w};
      const float bya[4] = {fy.x, fy.y, fy.z, fy.w};
      const float bza[4] = {fz.x, fz.y, fz.z, fz.w};
#pragma unroll
      for (int e = 0; e < 4; ++e) {
        const float bx = bxa[e], by = bya[e], bz = bza[e];
        float d[8];
#pragma unroll
        for (int h = 0; h < 8; ++h)
          d[h] = fmaf(CK[h].x, bx, fmaf(CK[h].y, by, fmaf(CK[h].z, bz, CK[h].w)));
        float mx = d[0];
#pragma unroll
        for (int h = 1; h < 8; ++h) mx = fmaxf(mx, d[h]);
        if (__any(mx > -CUT)) {    // rare: ~1 survivor per row over all S
#pragma unroll
          for (int h = 0; h < 8; ++h) {
            unsigned long long bm = __ballot(d[h] > -CUT);
            while (bm) {           // fixed LSB->MSB order: deterministic
              const int l = (int)__ffsll(bm) - 1;
              bm &= bm - 1;
              const int dbits = __builtin_amdgcn_readlane(__float_as_int(d[h]), l);
              const float pr = exp2f(__int_as_float(dbits));
              lr[h] += pr;
              const uint32_t t =
                  (uint32_t)(q * QT + half * 512 + (grp << 8) + (l << 2) + e);
              if (keep_mask(((rg0 + (uint32_t)h) << 12) + t)) {
                const float* pa = x1g + 3u * t;   // uniform addr, rare
                const float a0 = pa[0], a1 = pa[1], a2 = pa[2];
                lk[h] += pr;
                o0[h] += pr * a0; o1[h] += pr * a1; o2[h] += pr * a2;
              }
            }
          }
        }
      }
    }
  }

  // accumulators are wave-uniform: lane 0 writes this wave's slot, no butterfly
  if (lane == 0) {
#pragma unroll
    for (int h = 0; h < 8; ++h) {
      WACC[wave][h][0] = lr[h];
      WACC[wave][h][1] = lk[h];
      WACC[wave][h][2] = o0[h];
      WACC[wave][h][3] = o1[h];
      WACC[wave][h][4] = o2[h];
    }
  }
  __syncthreads();

  // epilogue: both wave slots share the same (exact) max -> plain adds
  if (tid < RPB) {
    const int pw = (tid >> 3) << 1;   // rows 0-7 -> waves 0,1; 8-15 -> 2,3
    const int hr = tid & 7;
    const float l  = WACC[pw][hr][0] + WACC[pw + 1][hr][0];
    const float lkp = WACC[pw][hr][1] + WACC[pw + 1][hr][1];
    const float a0 = WACC[pw][hr][2] + WACC[pw + 1][hr][2];
    const float a1 = WACC[pw][hr][3] + WACC[pw + 1][hr][3];
    const float a2 = WACC[pw][hr][4] + WACC[pw + 1][hr][4];
    const float sc = 2.0f / l;  // includes 1/(1-p_drop) = 2
    float o[8];
#pragma unroll
    for (int h = 0; h < 8; ++h)
      o[h] = (bv[h] * lkp + Wv[h * 3 + 0] * a0 + Wv[h * 3 + 1] * a1 +
              Wv[h * 3 + 2] * a2) * sc;
    float4* po = (float4*)(out + (size_t)(g * S + row0 + tid) * 8);
    po[0] = make_float4(o[0], o[1], o[2], o[3]);
    po[1] = make_float4(o[4], o[5], o[6], o[7]);
  }
}

}  // namespace

extern "C" void kernel_launch(void* const* d_in, const int* in_sizes, int n_in,
                              void* d_out, int out_size, void* d_ws, size_t ws_size,
                              hipStream_t stream) {
  (void)in_sizes; (void)n_in; (void)d_ws; (void)ws_size; (void)out_size;
  const float* x1 = (const float*)d_in[0];
  const float* x2 = (const float*)d_in[1];
  const float* Wq = (const float*)d_in[2];
  const float* bq = (const float*)d_in[3];
  const float* Wk = (const float*)d_in[4];
  const float* bk = (const float*)d_in[5];
  const float* Wv = (const float*)d_in[6];
  const float* bv = (const float*)d_in[7];
  float* out = (float*)d_out;

  fused_attn<<<dim3(G * (S / RPB)), dim3(256), 0, stream>>>(
      x1, x2, Wq, bq, Wk, bk, Wv, bv, out);
}

// Round 6
// 94.755 us; speedup vs baseline: 3.3130x; 1.0845x over previous
//
#include <hip/hip_runtime.h>
#include <stdint.h>

namespace {

constexpr int G = 8;
constexpr int S = 4096;    // sequence length
constexpr int RPB = 64;    // rows per block (4 waves x 16)
constexpr int RPW = 16;    // rows per wave
constexpr int LOGCAP = 128;  // survivor log entries per wave (expect ~25)
// SCALE * log2(e):  2^10.5 * 1.4426950408889634
constexpr float K2C = (float)(1448.15468787004945 * 1.44269504088896340736);
// terms with d < -CUT contribute < 2^-32 each to l (l >= 1) -> invisible in fp32
constexpr float CUT = 32.0f;

__device__ __forceinline__ uint32_t rotl32(uint32_t x, uint32_t n) {
  return (x << n) | (x >> (32u - n));
}

__device__ __forceinline__ void tfround(uint32_t& x0, uint32_t& x1, uint32_t r) {
  x0 += x1;
  x1 = rotl32(x1, r);
  x1 ^= x0;
}

// threefry2x32 with key (0, 42)  [jax.random.key(42) -> (hi,lo)=(0,42)]
__device__ __forceinline__ void threefry2x32(uint32_t c0, uint32_t c1,
                                             uint32_t& r0, uint32_t& r1) {
  const uint32_t ks0 = 0u;
  const uint32_t ks1 = 42u;
  const uint32_t ks2 = 0x1BD11BF0u;  // 0 ^ 42 ^ 0x1BD11BDA
  uint32_t x0 = c0 + ks0;
  uint32_t x1 = c1 + ks1;
  tfround(x0, x1, 13); tfround(x0, x1, 15); tfround(x0, x1, 26); tfround(x0, x1, 6);
  x0 += ks1; x1 += ks2 + 1u;
  tfround(x0, x1, 17); tfround(x0, x1, 29); tfround(x0, x1, 16); tfround(x0, x1, 24);
  x0 += ks2; x1 += ks0 + 2u;
  tfround(x0, x1, 13); tfround(x0, x1, 15); tfround(x0, x1, 26); tfround(x0, x1, 6);
  x0 += ks0; x1 += ks1 + 3u;
  tfround(x0, x1, 17); tfround(x0, x1, 29); tfround(x0, x1, 16); tfround(x0, x1, 24);
  x0 += ks1; x1 += ks2 + 4u;
  tfround(x0, x1, 13); tfround(x0, x1, 15); tfround(x0, x1, 26); tfround(x0, x1, 6);
  x0 += ks2; x1 += ks0 + 5u;
  r0 = x0; r1 = x1;
}

// keep element iff uniform(i) < 0.5  <=>  MSB(x0^x1) == 0  (partitionable PRNG)
__device__ __forceinline__ bool keep_mask(uint32_t i) {
  uint32_t a, b;
  threefry2x32(0u, i, a, b);   // hi32(index)=0 since total size = 2^27
  return (((a ^ b) >> 31) == 0u);
}

__global__ __launch_bounds__(256)
void fused_attn(const float* __restrict__ x1, const float* __restrict__ x2,
                const float* __restrict__ Wq, const float* __restrict__ bq,
                const float* __restrict__ Wk, const float* __restrict__ bk,
                const float* __restrict__ Wv, const float* __restrict__ bv,
                float* __restrict__ out) {
  __shared__ __align__(16) float XS[S];     // SoA x-comp of x2(g), 16 KB
  __shared__ __align__(16) float YS[S];
  __shared__ __align__(16) float ZS[S];
  __shared__ float4 CKs[RPB];               // per-row folded K coeffs
  __shared__ uint32_t LOGB[4][LOGCAP * 2];  // per-wave survivor log

  const int g = blockIdx.x >> 6;        // 0..7
  const int tile = blockIdx.x & 63;     // 0..63
  const int row0 = tile * RPB;          // first row of block (within group)
  const int tid = (int)threadIdx.x;
  const int wave = tid >> 6;
  const int lane = tid & 63;

  const float* x2g = x2 + (size_t)g * S * 3;
  const float* x1g = x1 + (size_t)g * S * 3;

  // --- threads 0..63: per-row low-rank coeffs  s2(t) = cK . x2[t] + c3 ---
  if (tid < RPB) {
    const float* px = x1g + (size_t)(row0 + tid) * 3;
    const float a0 = px[0], a1 = px[1], a2 = px[2];
    float q[8];
#pragma unroll
    for (int h = 0; h < 8; ++h)
      q[h] = bq[h] + a0 * Wq[h * 3 + 0] + a1 * Wq[h * 3 + 1] + a2 * Wq[h * 3 + 2];
    float t0 = 0.f, t1 = 0.f, t2 = 0.f, t3 = 0.f;
#pragma unroll
    for (int h = 0; h < 8; ++h) {
      t0 += q[h] * Wk[h * 3 + 0];
      t1 += q[h] * Wk[h * 3 + 1];
      t2 += q[h] * Wk[h * 3 + 2];
      t3 += q[h] * bk[h];
    }
    CKs[tid] = make_float4(t0 * K2C, t1 * K2C, t2 * K2C, t3 * K2C);
  }

  // --- stage ALL of x2(g) into SoA LDS once: 12 upfront float4 loads ---
  {
    const float4* src = (const float4*)x2g;
    float4* X4 = (float4*)XS;
    float4* Y4 = (float4*)YS;
    float4* Z4 = (float4*)ZS;
    float4 tmp[12];
#pragma unroll
    for (int it = 0; it < 4; ++it)
#pragma unroll
      for (int k = 0; k < 3; ++k)
        tmp[it * 3 + k] = src[it * 768 + tid * 3 + k];
#pragma unroll
    for (int it = 0; it < 4; ++it) {
      const float4 f0 = tmp[it * 3 + 0];
      const float4 f1 = tmp[it * 3 + 1];
      const float4 f2 = tmp[it * 3 + 2];
      const int gi = it * 256 + tid;
      X4[gi] = make_float4(f0.x, f0.w, f1.z, f2.y);
      Y4[gi] = make_float4(f0.y, f1.x, f1.w, f2.z);
      Z4[gi] = make_float4(f0.z, f1.y, f2.x, f2.w);
    }
  }
  __syncthreads();   // the ONLY block-wide barrier

  const float4* X4 = (const float4*)XS;
  const float4* Y4 = (const float4*)YS;
  const float4* Z4 = (const float4*)ZS;

  float4 CK[RPW];
#pragma unroll
  for (int r = 0; r < RPW; ++r) CK[r] = CKs[wave * RPW + r];  // LDS broadcast

  // ---------------- phase 1: exact row max over full S (wave-local) ---------
  float m[RPW];
#pragma unroll
  for (int r = 0; r < RPW; ++r) m[r] = -3.0e38f;

#pragma unroll 2
  for (int c = 0; c < S / 4 / 64; ++c) {   // 16 iters, 64 t-groups each
    const int i4 = (c << 6) + lane;
    const float4 fx = X4[i4], fy = Y4[i4], fz = Z4[i4];
    const float bxa[4] = {fx.x, fx.y, fx.z, fx.w};
    const float bya[4] = {fy.x, fy.y, fy.z, fy.w};
    const float bza[4] = {fz.x, fz.y, fz.z, fz.w};
#pragma unroll
    for (int e = 0; e < 4; ++e) {
      const float bx = bxa[e], by = bya[e], bz = bza[e];
#pragma unroll
      for (int r = 0; r < RPW; ++r)
        m[r] = fmaxf(m[r], fmaf(CK[r].x, bx,
                     fmaf(CK[r].y, by, fmaf(CK[r].z, bz, CK[r].w))));
    }
  }
#pragma unroll
  for (int msk = 1; msk < 64; msk <<= 1) {
#pragma unroll
    for (int r = 0; r < RPW; ++r) m[r] = fmaxf(m[r], __shfl_xor(m[r], msk, 64));
  }
#pragma unroll
  for (int r = 0; r < RPW; ++r) CK[r].w -= m[r];  // now scores come out as d=s2-max

  // ---------------- phase 2: scan + log survivors (no inline events) --------
  uint32_t* LOG = LOGB[wave];
  int cnt = 0;

#pragma unroll 2
  for (int c = 0; c < S / 4 / 64; ++c) {
    const int i4 = (c << 6) + lane;
    const float4 fx = X4[i4], fy = Y4[i4], fz = Z4[i4];
    const float bxa[4] = {fx.x, fx.y, fx.z, fx.w};
    const float bya[4] = {fy.x, fy.y, fy.z, fy.w};
    const float bza[4] = {fz.x, fz.y, fz.z, fz.w};
#pragma unroll
    for (int e = 0; e < 4; ++e) {
      const float bx = bxa[e], by = bya[e], bz = bza[e];
      float d[RPW];
#pragma unroll
      for (int r = 0; r < RPW; ++r)
        d[r] = fmaf(CK[r].x, bx, fmaf(CK[r].y, by, fmaf(CK[r].z, bz, CK[r].w)));
      // max tree (compiler folds to v_max3)
      float m01 = fmaxf(fmaxf(d[0], d[1]), fmaxf(d[2], d[3]));
      float m23 = fmaxf(fmaxf(d[4], d[5]), fmaxf(d[6], d[7]));
      float m45 = fmaxf(fmaxf(d[8], d[9]), fmaxf(d[10], d[11]));
      float m67 = fmaxf(fmaxf(d[12], d[13]), fmaxf(d[14], d[15]));
      const float mx = fmaxf(fmaxf(m01, m23), fmaxf(m45, m67));
      if (__any(mx > -CUT)) {
        const uint32_t tt = (uint32_t)((i4 << 2) + e);
#pragma unroll
        for (int r = 0; r < RPW; ++r) {
          const bool hit = (d[r] > -CUT);
          const unsigned long long bm = __ballot(hit);
          if (bm) {
            const int pos =
                cnt + (int)__popcll(bm & ((1ull << lane) - 1ull));
            if (hit && pos < LOGCAP) {
              LOG[pos * 2 + 0] = ((uint32_t)r << 12) | tt;
              LOG[pos * 2 + 1] = __float_as_uint(d[r]);
            }
            cnt += (int)__popcll(bm);
          }
        }
      }
    }
  }
  if (cnt > LOGCAP) cnt = LOGCAP;

  // ---------------- epilogue: batch-process the survivor log ----------------
  const uint32_t grow0 = (uint32_t)(g * S + row0 + wave * RPW);
  float lr = 0.f, lkp = 0.f, a0 = 0.f, a1 = 0.f, a2 = 0.f;  // per row-lane

  for (int base = 0; base < cnt; base += 64) {
    const int idx = base + lane;
    const bool val = (idx < cnt);
    const uint32_t w0 = val ? LOG[idx * 2 + 0] : 0u;
    const float dd = val ? __uint_as_float(LOG[idx * 2 + 1]) : 0.0f;
    const int er = (int)(w0 >> 12);
    const uint32_t et = w0 & 4095u;
    const float pr = val ? exp2f(dd) : 0.0f;
    const bool keep = val && keep_mask(((grow0 + (uint32_t)er) << 12) | et);
    float c0 = 0.f, c1 = 0.f, c2 = 0.f, prk = 0.f;
    if (keep) {
      const float* pa = x1g + 3u * et;
      prk = pr;
      c0 = pr * pa[0]; c1 = pr * pa[1]; c2 = pr * pa[2];
    }
    const int nj = (cnt - base < 64) ? (cnt - base) : 64;
    for (int jj = 0; jj < nj; ++jj) {   // uniform loop, shfl-broadcast reduce
      const int rj = __shfl(er, jj, 64);
      const float prj = __shfl(pr, jj, 64);
      const float prkj = __shfl(prk, jj, 64);
      const float c0j = __shfl(c0, jj, 64);
      const float c1j = __shfl(c1, jj, 64);
      const float c2j = __shfl(c2, jj, 64);
      const bool mine = (rj == lane);   // only lanes 0..15 ever match a row
      lr += mine ? prj : 0.f;
      lkp += mine ? prkj : 0.f;
      a0 += mine ? c0j : 0.f;
      a1 += mine ? c1j : 0.f;
      a2 += mine ? c2j : 0.f;
    }
  }

  if (lane < RPW) {
    const int srow = row0 + wave * RPW + lane;   // within group
    const float sc = 2.0f / lr;  // includes 1/(1-p_drop) = 2
    float o[8];
#pragma unroll
    for (int h = 0; h < 8; ++h)
      o[h] = (bv[h] * lkp + Wv[h * 3 + 0] * a0 + Wv[h * 3 + 1] * a1 +
              Wv[h * 3 + 2] * a2) * sc;
    float4* po = (float4*)(out + (size_t)(g * S + srow) * 8);
    po[0] = make_float4(o[0], o[1], o[2], o[3]);
    po[1] = make_float4(o[4], o[5], o[6], o[7]);
  }
}

}  // namespace

extern "C" void kernel_launch(void* const* d_in, const int* in_sizes, int n_in,
                              void* d_out, int out_size, void* d_ws, size_t ws_size,
                              hipStream_t stream) {
  (void)in_sizes; (void)n_in; (void)d_ws; (void)ws_size; (void)out_size;
  const float* x1 = (const float*)d_in[0];
  const float* x2 = (const float*)d_in[1];
  const float* Wq = (const float*)d_in[2];
  const float* bq = (const float*)d_in[3];
  const float* Wk = (const float*)d_in[4];
  const float* bk = (const float*)d_in[5];
  const float* Wv = (const float*)d_in[6];
  const float* bv = (const float*)d_in[7];
  float* out = (float*)d_out;

  // 8 groups x 64 row-tiles of 64 rows; 512 blocks -> all co-resident
  fused_attn<<<dim3(G * (S / RPB)), dim3(256), 0, stream>>>(
      x1, x2, Wq, bq, Wk, bk, Wv, bv, out);
}

// Round 7
// 91.823 us; speedup vs baseline: 3.4187x; 1.0319x over previous
//
#include <hip/hip_runtime.h>
#include <stdint.h>

namespace {

constexpr int G = 8;
constexpr int S = 4096;    // sequence length
constexpr int RPB = 64;    // rows per block (8 waves x 8)
constexpr int RPW = 8;     // rows per wave
constexpr int NW = 8;      // waves per block
constexpr int LOGCAP = 64; // survivor log entries per wave (expect ~12)
// SCALE * log2(e):  2^10.5 * 1.4426950408889634
constexpr float K2C = (float)(1448.15468787004945 * 1.44269504088896340736);
// terms with d < -CUT contribute < 2^-32 each to l (l >= 1) -> invisible in fp32
constexpr float CUT = 32.0f;

__device__ __forceinline__ uint32_t rotl32(uint32_t x, uint32_t n) {
  return (x << n) | (x >> (32u - n));
}

__device__ __forceinline__ void tfround(uint32_t& x0, uint32_t& x1, uint32_t r) {
  x0 += x1;
  x1 = rotl32(x1, r);
  x1 ^= x0;
}

// threefry2x32 with key (0, 42)  [jax.random.key(42) -> (hi,lo)=(0,42)]
__device__ __forceinline__ void threefry2x32(uint32_t c0, uint32_t c1,
                                             uint32_t& r0, uint32_t& r1) {
  const uint32_t ks0 = 0u;
  const uint32_t ks1 = 42u;
  const uint32_t ks2 = 0x1BD11BF0u;  // 0 ^ 42 ^ 0x1BD11BDA
  uint32_t x0 = c0 + ks0;
  uint32_t x1 = c1 + ks1;
  tfround(x0, x1, 13); tfround(x0, x1, 15); tfround(x0, x1, 26); tfround(x0, x1, 6);
  x0 += ks1; x1 += ks2 + 1u;
  tfround(x0, x1, 17); tfround(x0, x1, 29); tfround(x0, x1, 16); tfround(x0, x1, 24);
  x0 += ks2; x1 += ks0 + 2u;
  tfround(x0, x1, 13); tfround(x0, x1, 15); tfround(x0, x1, 26); tfround(x0, x1, 6);
  x0 += ks0; x1 += ks1 + 3u;
  tfround(x0, x1, 17); tfround(x0, x1, 29); tfround(x0, x1, 16); tfround(x0, x1, 24);
  x0 += ks1; x1 += ks2 + 4u;
  tfround(x0, x1, 13); tfround(x0, x1, 15); tfround(x0, x1, 26); tfround(x0, x1, 6);
  x0 += ks2; x1 += ks0 + 5u;
  r0 = x0; r1 = x1;
}

// keep element iff uniform(i) < 0.5  <=>  MSB(x0^x1) == 0  (partitionable PRNG)
__device__ __forceinline__ bool keep_mask(uint32_t i) {
  uint32_t a, b;
  threefry2x32(0u, i, a, b);   // hi32(index)=0 since total size = 2^27
  return (((a ^ b) >> 31) == 0u);
}

__global__ __launch_bounds__(512, 4)
void fused_attn(const float* __restrict__ x1, const float* __restrict__ x2,
                const float* __restrict__ Wq, const float* __restrict__ bq,
                const float* __restrict__ Wk, const float* __restrict__ bk,
                const float* __restrict__ Wv, const float* __restrict__ bv,
                float* __restrict__ out) {
  __shared__ __align__(16) float XS[S];      // SoA x-comp of x2(g), 16 KB
  __shared__ __align__(16) float YS[S];
  __shared__ __align__(16) float ZS[S];
  __shared__ float4 CKs[RPB];                // per-row folded K coeffs
  __shared__ uint32_t LOGB[NW][LOGCAP * 2];  // per-wave survivor log

  const int g = blockIdx.x >> 6;        // 0..7
  const int tile = blockIdx.x & 63;     // 0..63
  const int row0 = tile * RPB;          // first row of block (within group)
  const int tid = (int)threadIdx.x;
  const int wave = tid >> 6;
  const int lane = tid & 63;

  const float* x2g = x2 + (size_t)g * S * 3;
  const float* x1g = x1 + (size_t)g * S * 3;

  // --- threads 0..63: per-row low-rank coeffs  s2(t) = cK . x2[t] + c3 ---
  if (tid < RPB) {
    const float* px = x1g + (size_t)(row0 + tid) * 3;
    const float a0 = px[0], a1 = px[1], a2 = px[2];
    float q[8];
#pragma unroll
    for (int h = 0; h < 8; ++h)
      q[h] = bq[h] + a0 * Wq[h * 3 + 0] + a1 * Wq[h * 3 + 1] + a2 * Wq[h * 3 + 2];
    float t0 = 0.f, t1 = 0.f, t2 = 0.f, t3 = 0.f;
#pragma unroll
    for (int h = 0; h < 8; ++h) {
      t0 += q[h] * Wk[h * 3 + 0];
      t1 += q[h] * Wk[h * 3 + 1];
      t2 += q[h] * Wk[h * 3 + 2];
      t3 += q[h] * bk[h];
    }
    CKs[tid] = make_float4(t0 * K2C, t1 * K2C, t2 * K2C, t3 * K2C);
  }

  // --- stage ALL of x2(g) into SoA LDS once: 6 upfront float4 loads/thread ---
  {
    const float4* src = (const float4*)x2g;
    float4* X4 = (float4*)XS;
    float4* Y4 = (float4*)YS;
    float4* Z4 = (float4*)ZS;
    float4 tmp[6];
#pragma unroll
    for (int it = 0; it < 2; ++it)
#pragma unroll
      for (int k = 0; k < 3; ++k)
        tmp[it * 3 + k] = src[it * 1536 + tid * 3 + k];
#pragma unroll
    for (int it = 0; it < 2; ++it) {
      const float4 f0 = tmp[it * 3 + 0];
      const float4 f1 = tmp[it * 3 + 1];
      const float4 f2 = tmp[it * 3 + 2];
      const int gi = it * 512 + tid;
      X4[gi] = make_float4(f0.x, f0.w, f1.z, f2.y);
      Y4[gi] = make_float4(f0.y, f1.x, f1.w, f2.z);
      Z4[gi] = make_float4(f0.z, f1.y, f2.x, f2.w);
    }
  }
  __syncthreads();   // the ONLY block-wide barrier

  const float4* X4 = (const float4*)XS;
  const float4* Y4 = (const float4*)YS;
  const float4* Z4 = (const float4*)ZS;

  float4 CK[RPW];
#pragma unroll
  for (int r = 0; r < RPW; ++r) CK[r] = CKs[wave * RPW + r];  // LDS broadcast

  // ---------------- phase 1: exact row max over full S (wave-local) ---------
  float m[RPW];
#pragma unroll
  for (int r = 0; r < RPW; ++r) m[r] = -3.0e38f;

#pragma unroll 2
  for (int c = 0; c < S / 4 / 64; ++c) {   // 16 iters, 64 t-groups each
    const int i4 = (c << 6) + lane;
    const float4 fx = X4[i4], fy = Y4[i4], fz = Z4[i4];
    const float bxa[4] = {fx.x, fx.y, fx.z, fx.w};
    const float bya[4] = {fy.x, fy.y, fy.z, fy.w};
    const float bza[4] = {fz.x, fz.y, fz.z, fz.w};
#pragma unroll
    for (int e = 0; e < 4; ++e) {
      const float bx = bxa[e], by = bya[e], bz = bza[e];
#pragma unroll
      for (int r = 0; r < RPW; ++r)
        m[r] = fmaxf(m[r], fmaf(CK[r].x, bx,
                     fmaf(CK[r].y, by, fmaf(CK[r].z, bz, CK[r].w))));
    }
  }
#pragma unroll
  for (int msk = 1; msk < 64; msk <<= 1) {
#pragma unroll
    for (int r = 0; r < RPW; ++r) m[r] = fmaxf(m[r], __shfl_xor(m[r], msk, 64));
  }
#pragma unroll
  for (int r = 0; r < RPW; ++r) CK[r].w -= m[r];  // scores now come out as d=s2-max

  // ---------------- phase 2: scan + log survivors (no inline events) --------
  uint32_t* LOG = LOGB[wave];
  int cnt = 0;

#pragma unroll 2
  for (int c = 0; c < S / 4 / 64; ++c) {
    const int i4 = (c << 6) + lane;
    const float4 fx = X4[i4], fy = Y4[i4], fz = Z4[i4];
    const float bxa[4] = {fx.x, fx.y, fx.z, fx.w};
    const float bya[4] = {fy.x, fy.y, fy.z, fy.w};
    const float bza[4] = {fz.x, fz.y, fz.z, fz.w};
#pragma unroll
    for (int e = 0; e < 4; ++e) {
      const float bx = bxa[e], by = bya[e], bz = bza[e];
      float d[RPW];
#pragma unroll
      for (int r = 0; r < RPW; ++r)
        d[r] = fmaf(CK[r].x, bx, fmaf(CK[r].y, by, fmaf(CK[r].z, bz, CK[r].w)));
      const float m01 = fmaxf(fmaxf(d[0], d[1]), fmaxf(d[2], d[3]));
      const float m23 = fmaxf(fmaxf(d[4], d[5]), fmaxf(d[6], d[7]));
      const float mx = fmaxf(m01, m23);
      if (__any(mx > -CUT)) {
        const uint32_t tt = (uint32_t)((i4 << 2) + e);
#pragma unroll
        for (int r = 0; r < RPW; ++r) {
          const bool hit = (d[r] > -CUT);
          const unsigned long long bm = __ballot(hit);
          if (bm) {
            const int pos = cnt + (int)__popcll(bm & ((1ull << lane) - 1ull));
            if (hit && pos < LOGCAP) {
              LOG[pos * 2 + 0] = ((uint32_t)r << 12) | tt;
              LOG[pos * 2 + 1] = __float_as_uint(d[r]);
            }
            cnt += (int)__popcll(bm);
          }
        }
      }
    }
  }
  if (cnt > LOGCAP) cnt = LOGCAP;

  // ---------------- epilogue: batch-process the survivor log ----------------
  const uint32_t grow0 = (uint32_t)(g * S + row0 + wave * RPW);
  float lr = 0.f, lkp = 0.f, a0 = 0.f, a1 = 0.f, a2 = 0.f;  // per row-lane

  for (int base = 0; base < cnt; base += 64) {
    const int idx = base + lane;
    const bool val = (idx < cnt);
    const uint32_t w0 = val ? LOG[idx * 2 + 0] : 0u;
    const float dd = val ? __uint_as_float(LOG[idx * 2 + 1]) : 0.0f;
    const int er = (int)(w0 >> 12);
    const uint32_t et = w0 & 4095u;
    const float pr = val ? exp2f(dd) : 0.0f;
    const bool keep = val && keep_mask(((grow0 + (uint32_t)er) << 12) | et);
    float c0 = 0.f, c1 = 0.f, c2 = 0.f, prk = 0.f;
    if (keep) {
      const float* pa = x1g + 3u * et;
      prk = pr;
      c0 = pr * pa[0]; c1 = pr * pa[1]; c2 = pr * pa[2];
    }
    const int nj = (cnt - base < 64) ? (cnt - base) : 64;
    for (int jj = 0; jj < nj; ++jj) {   // uniform loop, shfl-broadcast reduce
      const int rj = __shfl(er, jj, 64);
      const float prj = __shfl(pr, jj, 64);
      const float prkj = __shfl(prk, jj, 64);
      const float c0j = __shfl(c0, jj, 64);
      const float c1j = __shfl(c1, jj, 64);
      const float c2j = __shfl(c2, jj, 64);
      const bool mine = (rj == lane);   // only lanes 0..7 ever match a row
      lr += mine ? prj : 0.f;
      lkp += mine ? prkj : 0.f;
      a0 += mine ? c0j : 0.f;
      a1 += mine ? c1j : 0.f;
      a2 += mine ? c2j : 0.f;
    }
  }

  if (lane < RPW) {
    const int srow = row0 + wave * RPW + lane;   // within group
    const float sc = 2.0f / lr;  // includes 1/(1-p_drop) = 2
    float o[8];
#pragma unroll
    for (int h = 0; h < 8; ++h)
      o[h] = (bv[h] * lkp + Wv[h * 3 + 0] * a0 + Wv[h * 3 + 1] * a1 +
              Wv[h * 3 + 2] * a2) * sc;
    float4* po = (float4*)(out + (size_t)(g * S + srow) * 8);
    po[0] = make_float4(o[0], o[1], o[2], o[3]);
    po[1] = make_float4(o[4], o[5], o[6], o[7]);
  }
}

}  // namespace

extern "C" void kernel_launch(void* const* d_in, const int* in_sizes, int n_in,
                              void* d_out, int out_size, void* d_ws, size_t ws_size,
                              hipStream_t stream) {
  (void)in_sizes; (void)n_in; (void)d_ws; (void)ws_size; (void)out_size;
  const float* x1 = (const float*)d_in[0];
  const float* x2 = (const float*)d_in[1];
  const float* Wq = (const float*)d_in[2];
  const float* bq = (const float*)d_in[3];
  const float* Wk = (const float*)d_in[4];
  const float* bk = (const float*)d_in[5];
  const float* Wv = (const float*)d_in[6];
  const float* bv = (const float*)d_in[7];
  float* out = (float*)d_out;

  // 8 groups x 64 row-tiles of 64 rows; 512 blocks, 2 resident per CU
  fused_attn<<<dim3(G * (S / RPB)), dim3(512), 0, stream>>>(
      x1, x2, Wq, bq, Wk, bk, Wv, bv, out);
}